// Round 1
// baseline (839.015 us; speedup 1.0000x reference)
//
#include <hip/hip_runtime.h>
#include <math.h>

typedef _Float16 f16x8 __attribute__((ext_vector_type(8)));
typedef float    f32x4 __attribute__((ext_vector_type(4)));

#define SEQ   2048
#define DH    64
#define BM    64            // q-rows per block (4 waves x 16 rows)
#define BK    64            // k-chunk per iteration
#define LOG2E 1.44269504088896340736f

// One wave = 16 q-rows, full Dh=64 (4 n-tiles of 16), flash-style online softmax.
// A-frag (16x16x32): A[m=lane&15][k=quad*8+j]  (verified layout, m120)
// B-frag:            B[k=quad*8+j][n=lane&15]  = x2[n][k]
// C/D:               n=lane&15, m=quad*4+reg   (verified layout, m89/m91)
extern "C" __global__ __launch_bounds__(256, 4)
void softmax_matmul_f16(const float* __restrict__ x1,
                        const float* __restrict__ x2,
                        float* __restrict__ out)
{
    const int tid  = threadIdx.x;
    const int wave = tid >> 6;
    const int lane = tid & 63;
    const int r    = lane & 15;     // q-row within wave tile / n within n-tile
    const int quad = lane >> 4;     // 0..3 -> k offset quad*8

    const int bh   = blockIdx.x >> 5;      // SEQ/BM = 32 q-blocks per bh
    const int qblk = blockIdx.x & 31;
    const int row0 = qblk * BM + wave * 16;

    const float* x1row = x1 + ((size_t)bh * SEQ + (size_t)(row0 + r)) * SEQ;
    const float* x2bh  = x2 + (size_t)bh * DH * SEQ;        // [64][2048]
    float*       obase = out + ((size_t)bh * SEQ + (size_t)row0) * DH;

    f32x4 acc[4];
#pragma unroll
    for (int t = 0; t < 4; ++t) acc[t] = (f32x4){0.f, 0.f, 0.f, 0.f};

    float m = -INFINITY;
    float l = 0.0f;

    // register prefetch of first x1 chunk (fragment pattern: 8 floats at quad*8, 8 at 32+quad*8)
    const float* pf = x1row + quad * 8;
    float4 n0 = *(const float4*)(pf + 0);
    float4 n1 = *(const float4*)(pf + 4);
    float4 n2 = *(const float4*)(pf + 32);
    float4 n3 = *(const float4*)(pf + 36);

    for (int k0 = 0; k0 < SEQ; k0 += BK) {
        float xv[16];
        xv[0] = n0.x; xv[1] = n0.y; xv[2]  = n0.z; xv[3]  = n0.w;
        xv[4] = n1.x; xv[5] = n1.y; xv[6]  = n1.z; xv[7]  = n1.w;
        xv[8] = n2.x; xv[9] = n2.y; xv[10] = n2.z; xv[11] = n2.w;
        xv[12] = n3.x; xv[13] = n3.y; xv[14] = n3.z; xv[15] = n3.w;

        const int k1 = k0 + BK;
        if (k1 < SEQ) {                       // uniform branch, no divergence
            const float* pn = x1row + k1 + quad * 8;
            n0 = *(const float4*)(pn + 0);
            n1 = *(const float4*)(pn + 4);
            n2 = *(const float4*)(pn + 32);
            n3 = *(const float4*)(pn + 36);
        }

        // ---- online softmax stats for this chunk (rows live in lanes {r,r+16,r+32,r+48})
        float cmax = xv[0];
#pragma unroll
        for (int j = 1; j < 16; ++j) cmax = fmaxf(cmax, xv[j]);
        cmax = fmaxf(cmax, __shfl_xor(cmax, 16));
        cmax = fmaxf(cmax, __shfl_xor(cmax, 32));

        const float mnew  = fmaxf(m, cmax);
        const float alpha = __builtin_amdgcn_exp2f((m - mnew) * LOG2E);
        const float sh    = mnew * LOG2E;

        float p[16];
        float rsum = 0.f;
#pragma unroll
        for (int j = 0; j < 16; ++j) {
            p[j] = __builtin_amdgcn_exp2f(__builtin_fmaf(xv[j], LOG2E, -sh));
            rsum += p[j];
        }
        rsum += __shfl_xor(rsum, 16);
        rsum += __shfl_xor(rsum, 32);
        l = l * alpha + rsum;
        m = mnew;

        // ---- rescale accumulators: alpha for C-row quad*4+g lives in lane (quad*4+g)
        float ar[4];
#pragma unroll
        for (int g = 0; g < 4; ++g) ar[g] = __shfl(alpha, quad * 4 + g);
#pragma unroll
        for (int t = 0; t < 4; ++t)
#pragma unroll
            for (int g = 0; g < 4; ++g) acc[t][g] *= ar[g];

        // ---- A fragments (fp16, RNE)
        f16x8 ah0, ah1;
#pragma unroll
        for (int j = 0; j < 8; ++j) {
            ah0[j] = (_Float16)p[j];
            ah1[j] = (_Float16)p[8 + j];
        }

        // ---- B fragments from x2 (L2-resident), 4 n-tiles x 2 k-steps
#pragma unroll
        for (int t = 0; t < 4; ++t) {
            const float* bp = x2bh + (size_t)(t * 16 + r) * SEQ + k0 + quad * 8;
            float4 b0 = *(const float4*)(bp + 0);
            float4 b1 = *(const float4*)(bp + 4);
            float4 b2 = *(const float4*)(bp + 32);
            float4 b3 = *(const float4*)(bp + 36);
            f16x8 bf0, bf1;
            bf0[0] = (_Float16)b0.x; bf0[1] = (_Float16)b0.y; bf0[2] = (_Float16)b0.z; bf0[3] = (_Float16)b0.w;
            bf0[4] = (_Float16)b1.x; bf0[5] = (_Float16)b1.y; bf0[6] = (_Float16)b1.z; bf0[7] = (_Float16)b1.w;
            bf1[0] = (_Float16)b2.x; bf1[1] = (_Float16)b2.y; bf1[2] = (_Float16)b2.z; bf1[3] = (_Float16)b2.w;
            bf1[4] = (_Float16)b3.x; bf1[5] = (_Float16)b3.y; bf1[6] = (_Float16)b3.z; bf1[7] = (_Float16)b3.w;
            acc[t] = __builtin_amdgcn_mfma_f32_16x16x32_f16(ah0, bf0, acc[t], 0, 0, 0);
            acc[t] = __builtin_amdgcn_mfma_f32_16x16x32_f16(ah1, bf1, acc[t], 0, 0, 0);
        }
    }

    // ---- epilogue: divide by l (per-row), store C layout rows quad*4+g, col t*16+r
    const float rl = 1.0f / l;
    float rlr[4];
#pragma unroll
    for (int g = 0; g < 4; ++g) rlr[g] = __shfl(rl, quad * 4 + g);
#pragma unroll
    for (int t = 0; t < 4; ++t)
#pragma unroll
        for (int g = 0; g < 4; ++g)
            obase[(size_t)(quad * 4 + g) * DH + t * 16 + r] = acc[t][g] * rlr[g];
}

extern "C" void kernel_launch(void* const* d_in, const int* in_sizes, int n_in,
                              void* d_out, int out_size, void* d_ws, size_t ws_size,
                              hipStream_t stream)
{
    const float* x1 = (const float*)d_in[0];
    const float* x2 = (const float*)d_in[1];
    float* out = (float*)d_out;

    const int bhCount = in_sizes[1] / (DH * SEQ);   // B*H = 32
    dim3 grid(bhCount * (SEQ / BM));                // 1024 blocks
    dim3 block(256);
    hipLaunchKernelGGL(softmax_matmul_f16, grid, block, 0, stream, x1, x2, out);
}